// Round 2
// baseline (427.447 us; speedup 1.0000x reference)
//
#include <hip/hip_runtime.h>
#include <stdint.h>

// ---------------------------------------------------------------------------
// Fused: Q=x@Wq^T+bq; K=y@Wk^T+bk; V=y@Wv^T+bv; ctx=softmax(QK^T/sqrt(384))@V
//        out = (x + ctx/||ctx||_row) @ Wo^T + bo        (N=M=8192, D=384)
// softmax: no max-subtraction needed (logit sigma ~0.33); denominator cancels
// under F.normalize. Scale*log2e folded into Q projection -> P = exp2(S).
// flash v2: 32x32x16 MFMA, S^T=mfma(K,Q) so P stays in registers
// (cvt_pk_bf16 + permlane32_swap build PV B-frags), K dbuf + V sbuf staged via
// global_load_lds w/ pre-swizzled source, raw s_barrier + counted vmcnt.
// ws layout: Qb bf16[8192,384]@0; Kb@6291456; Vt bf16[384,8192]@12582912;
//            Xn bf16[8192,384]@18874368; ctx f32[4][8192,384]@25165824
// ---------------------------------------------------------------------------

typedef __attribute__((ext_vector_type(8))) short bf16x8;
typedef __attribute__((ext_vector_type(4))) float f32x4;
typedef __attribute__((ext_vector_type(16))) float f32x16;

#define DEV static __device__ __forceinline__

DEV short f2bf(float f) {
  uint32_t u = __builtin_bit_cast(uint32_t, f);
  u += 0x7fffu + ((u >> 16) & 1u);
  return (short)(u >> 16);
}
DEV uint32_t pack2(float a, float b) {
  return (uint32_t)(uint16_t)f2bf(a) | ((uint32_t)(uint16_t)f2bf(b) << 16);
}
DEV unsigned cvt_pk(float lo, float hi) {
  unsigned r;
  asm("v_cvt_pk_bf16_f32 %0, %1, %2" : "=v"(r) : "v"(lo), "v"(hi));
  return r;
}
DEV void pl32swap(unsigned& a, unsigned& b) {
  asm volatile("v_permlane32_swap_b32 %0, %1" : "+v"(a), "+v"(b));
}
DEV void gload16(const void* g, void* l) {
  __builtin_amdgcn_global_load_lds(
      (const __attribute__((address_space(1))) unsigned*)g,
      (__attribute__((address_space(3))) unsigned*)l, 16, 0, 0);
}

// ---------------------------------------------------------------------------
// Generic GEMM-NT: C[m,n] = (sum_k A[m,k]*B[n,k] + bias) * scale
// ---------------------------------------------------------------------------
template <int BIAS_ON_N, int OUT_F32, int A_F32>
__global__ __launch_bounds__(256) void gemm_nt(
    const void* __restrict__ Aptr, const float* __restrict__ B,
    const float* __restrict__ bias, void* __restrict__ Cptr,
    int M, int N, int K, float scale) {
  __shared__ char As[128 * 128];
  __shared__ char Bs[128 * 128];
  const int tid = threadIdx.x;
  const int l = tid & 63, w = tid >> 6;
  const int lq = l & 15, lk = l >> 4;
  const int m0 = blockIdx.x * 128, n0 = blockIdx.y * 128;
  const int wr = (w >> 1) * 64, wc = (w & 1) * 64;
  f32x4 acc[4][4] = {};

  for (int k0 = 0; k0 < K; k0 += 64) {
    if (A_F32) {
      const float* A = (const float*)Aptr;
#pragma unroll
      for (int i = 0; i < 8; i++) {
        int c = tid + i * 256;
        int row = c >> 4, col = (c & 15) * 4;
        f32x4 v = *(const f32x4*)(A + (size_t)(m0 + row) * K + k0 + col);
        uint32_t lo = pack2(v.x, v.y), hi = pack2(v.z, v.w);
        int off = (row * 128 + col * 2) ^ ((row & 7) << 4);
        *(uint32_t*)(As + off) = lo;
        *(uint32_t*)(As + off + 4) = hi;
      }
    } else {
      const short* A = (const short*)Aptr;
#pragma unroll
      for (int i = 0; i < 4; i++) {
        int c = tid + i * 256;
        int row = c >> 3, col = (c & 7) * 8;
        uint4 v = *(const uint4*)(A + (size_t)(m0 + row) * K + k0 + col);
        int off = (row * 128 + col * 2) ^ ((row & 7) << 4);
        *(uint4*)(As + off) = v;
      }
    }
#pragma unroll
    for (int i = 0; i < 8; i++) {
      int c = tid + i * 256;
      int row = c >> 4, col = (c & 15) * 4;
      f32x4 v = *(const f32x4*)(B + (size_t)(n0 + row) * K + k0 + col);
      uint32_t lo = pack2(v.x, v.y), hi = pack2(v.z, v.w);
      int off = (row * 128 + col * 2) ^ ((row & 7) << 4);
      *(uint32_t*)(Bs + off) = lo;
      *(uint32_t*)(Bs + off + 4) = hi;
    }
    __syncthreads();
#pragma unroll
    for (int ks = 0; ks < 2; ks++) {
      bf16x8 af[4], bfr[4];
#pragma unroll
      for (int m = 0; m < 4; m++) {
        int row = wr + m * 16 + lq;
        af[m] = *(const bf16x8*)(As + ((row * 128 + ks * 64 + lk * 16) ^ ((row & 7) << 4)));
      }
#pragma unroll
      for (int n = 0; n < 4; n++) {
        int row = wc + n * 16 + lq;
        bfr[n] = *(const bf16x8*)(Bs + ((row * 128 + ks * 64 + lk * 16) ^ ((row & 7) << 4)));
      }
#pragma unroll
      for (int m = 0; m < 4; m++)
#pragma unroll
        for (int n = 0; n < 4; n++)
          acc[m][n] = __builtin_amdgcn_mfma_f32_16x16x32_bf16(af[m], bfr[n], acc[m][n], 0, 0, 0);
    }
    __syncthreads();
  }
#pragma unroll
  for (int m = 0; m < 4; m++) {
    int mg = m0 + wr + m * 16 + lk * 4;
#pragma unroll
    for (int n = 0; n < 4; n++) {
      int ng = n0 + wc + n * 16 + lq;
#pragma unroll
      for (int r = 0; r < 4; r++) {
        float v = (acc[m][n][r] + (BIAS_ON_N ? bias[ng] : bias[mg + r])) * scale;
        if (OUT_F32)
          ((float*)Cptr)[(size_t)(mg + r) * N + ng] = v;
        else
          ((short*)Cptr)[(size_t)(mg + r) * N + ng] = f2bf(v);
      }
    }
  }
}

// ---------------------------------------------------------------------------
// Flash numerator v2. Grid 512 = 128 q-tiles x 4 splits (split = bid&3, XCD-
// aligned). Block 256 = 4 waves: wave w = (q-group w>>1, d-half w&1).
// Per wave: S^T[32kv x 32q] = mfma(K-frag, Q-frag regs); P in regs via
// cvt_pk+permlane32_swap; ctx^T[dhalf][32q] += mfma(V-frag, P^T-frag).
// K: [32][768B] XOR-swz (row&7)<<4, double-buffered. V^T: [384][64B] XOR-swz
// ((row>>1)&3)<<4, single-buffered. Both DMA'd with pre-swizzled gsrc.
// ---------------------------------------------------------------------------
#define ITERS 64

__global__ __launch_bounds__(256, 2) void flash_attn(
    const short* __restrict__ Qb, const short* __restrict__ Kb,
    const short* __restrict__ Vt, float* __restrict__ ctx_part) {
  __shared__ char Ks[2][24576];
  __shared__ char Vs[24576];
  const int tid = threadIdx.x, l = tid & 63, w = tid >> 6;
  const int l31 = l & 31, h = l >> 5;
  const int qh = w >> 1, dh = w & 1;
  const int sp = blockIdx.x & 3, qt = blockIdx.x >> 2;
  const int q0 = qt * 64 + qh * 32;
  const int kvbase = sp * 2048;

  // Q B-frags resident: col q = q0+l31, k = s*16 + h*8 + j  (96 VGPR)
  bf16x8 qf[24];
  {
    const short* qrow = Qb + (size_t)(q0 + l31) * 384 + h * 8;
#pragma unroll
    for (int s = 0; s < 24; s++) qf[s] = *(const bf16x8*)(qrow + s * 16);
  }
  asm volatile("s_waitcnt vmcnt(0)" ::: "memory");

  // stage K(0) into Ks[0]
  {
#pragma unroll
    for (int i = 0; i < 6; i++) {
      int d = (w * 6 + i) * 1024 + l * 16;
      int row = d / 768, c = d - row * 768;
      int csrc = c ^ ((row & 7) << 4);
      gload16((const char*)Kb + (size_t)(kvbase + row) * 768 + csrc,
              (char*)Ks[0] + (w * 6 + i) * 1024);
    }
  }

  f32x16 acc[6] = {};

#pragma unroll 1
  for (int t = 0; t < ITERS; t++) {
    const char* Kc = Ks[t & 1];
    // ---- stage V(t) (Vbuf free since barrier C of t-1) ----
    {
      int kv0 = kvbase + t * 32;
#pragma unroll
      for (int i = 0; i < 6; i++) {
        int d = (w * 6 + i) * 1024 + l * 16;
        int vrow = d >> 6, c = d & 63;
        int csrc = c ^ (((vrow >> 1) & 3) << 4);
        gload16((const char*)Vt + (size_t)vrow * 16384 + kv0 * 2 + csrc,
                Vs + (w * 6 + i) * 1024);
      }
    }
    asm volatile("s_waitcnt vmcnt(6)" ::: "memory");  // K(t) landed, V(t) in flight
    __builtin_amdgcn_s_barrier();                     // A: K(t) visible block-wide

    // ---- S^T = K Q^T : two accumulation chains ----
    f32x16 S0 = {}, S1 = {};
    const int swzk = (l31 & 7) << 4;
    __builtin_amdgcn_s_setprio(1);
#pragma unroll
    for (int s = 0; s < 24; s += 2) {
      bf16x8 k0 = *(const bf16x8*)(Kc + l31 * 768 + ((s * 32 + h * 16) ^ swzk));
      bf16x8 k1 = *(const bf16x8*)(Kc + l31 * 768 + (((s + 1) * 32 + h * 16) ^ swzk));
      S0 = __builtin_amdgcn_mfma_f32_32x32x16_bf16(k0, qf[s], S0, 0, 0, 0);
      S1 = __builtin_amdgcn_mfma_f32_32x32x16_bf16(k1, qf[s + 1], S1, 0, 0, 0);
    }
    __builtin_amdgcn_s_setprio(0);

    // ---- stage K(t+1) into other buffer (overlaps softmax VALU) ----
    if (t < ITERS - 1) {
      int kv0 = kvbase + (t + 1) * 32;
      char* Kn = (char*)Ks[(t & 1) ^ 1];
#pragma unroll
      for (int i = 0; i < 6; i++) {
        int d = (w * 6 + i) * 1024 + l * 16;
        int row = d / 768, c = d - row * 768;
        int csrc = c ^ ((row & 7) << 4);
        gload16((const char*)Kb + (size_t)(kv0 + row) * 768 + csrc, Kn + (w * 6 + i) * 1024);
      }
    }

    // ---- P = exp2(S^T) in-register; build PV B-frags (kv = s*16+h*8+j, col q) ----
    float p[16];
#pragma unroll
    for (int i = 0; i < 16; i++) p[i] = __builtin_amdgcn_exp2f(S0[i] + S1[i]);
    unsigned a0 = cvt_pk(p[0], p[1]), a1 = cvt_pk(p[2], p[3]);
    unsigned a2 = cvt_pk(p[4], p[5]), a3 = cvt_pk(p[6], p[7]);
    pl32swap(a0, a2); pl32swap(a1, a3);
    uint4 pw0 = {a0, a1, a2, a3};
    bf16x8 pf0 = __builtin_bit_cast(bf16x8, pw0);
    unsigned b0 = cvt_pk(p[8], p[9]), b1 = cvt_pk(p[10], p[11]);
    unsigned b2 = cvt_pk(p[12], p[13]), b3 = cvt_pk(p[14], p[15]);
    pl32swap(b0, b2); pl32swap(b1, b3);
    uint4 pw1 = {b0, b1, b2, b3};
    bf16x8 pf1 = __builtin_bit_cast(bf16x8, pw1);

    if (t < ITERS - 1)
      asm volatile("s_waitcnt vmcnt(6)" ::: "memory");  // V(t) landed, K(t+1) in flight
    else
      asm volatile("s_waitcnt vmcnt(0)" ::: "memory");
    __builtin_amdgcn_s_barrier();                       // B: V(t) visible block-wide

    // ---- ctx^T += V^T P^T  (6 d-frags x 2 kv-steps) ----
    __builtin_amdgcn_s_setprio(1);
#pragma unroll
    for (int nf = 0; nf < 6; nf++) {
      int vr = dh * 192 + nf * 32 + l31;
      int swz = ((vr >> 1) & 3) << 4;
      bf16x8 v0 = *(const bf16x8*)(Vs + vr * 64 + ((h * 16) ^ swz));
      bf16x8 v1 = *(const bf16x8*)(Vs + vr * 64 + ((32 + h * 16) ^ swz));
      acc[nf] = __builtin_amdgcn_mfma_f32_32x32x16_bf16(v0, pf0, acc[nf], 0, 0, 0);
      acc[nf] = __builtin_amdgcn_mfma_f32_32x32x16_bf16(v1, pf1, acc[nf], 0, 0, 0);
    }
    __builtin_amdgcn_s_setprio(0);
    __builtin_amdgcn_s_barrier();  // C: V consumption done -> Vbuf reusable
  }

  // ---- epilogue: ctx^T frags -> ctx_part[sp][q][d]; lane owns one q row ----
  float* outp = ctx_part + (size_t)sp * 8192 * 384 + (size_t)(q0 + l31) * 384;
#pragma unroll
  for (int nf = 0; nf < 6; nf++) {
#pragma unroll
    for (int qd = 0; qd < 4; qd++) {
      f32x4 v = {acc[nf][qd * 4 + 0], acc[nf][qd * 4 + 1],
                 acc[nf][qd * 4 + 2], acc[nf][qd * 4 + 3]};
      *(f32x4*)(outp + dh * 192 + nf * 32 + qd * 8 + h * 4) = v;
    }
  }
}

// ---------------------------------------------------------------------------
// Combine: ctx = sum splits; Xn = bf16(x + ctx/||ctx||)  (denominator of
// softmax cancelled analytically). One wave per q row.
// ---------------------------------------------------------------------------
__global__ __launch_bounds__(256) void combine_norm(
    const float* __restrict__ ctx_part, const float* __restrict__ x,
    short* __restrict__ Xn) {
  const int l = threadIdx.x & 63, w = threadIdx.x >> 6;
  const int q = blockIdx.x * 4 + w;
  const size_t SLAB = (size_t)8192 * 384;
  float v[6];
  float ss = 0.f;
#pragma unroll
  for (int i = 0; i < 6; i++) {
    size_t off = (size_t)q * 384 + i * 64 + l;
    float s = ctx_part[off] + ctx_part[off + SLAB] + ctx_part[off + 2 * SLAB] +
              ctx_part[off + 3 * SLAB];
    v[i] = s;
    ss += s * s;
  }
#pragma unroll
  for (int m = 1; m <= 32; m <<= 1) ss += __shfl_xor(ss, m);
  float inv = 1.0f / fmaxf(sqrtf(ss), 1e-12f);
#pragma unroll
  for (int i = 0; i < 6; i++) {
    size_t off = (size_t)q * 384 + i * 64 + l;
    Xn[off] = f2bf(x[off] + v[i] * inv);
  }
}

// ---------------------------------------------------------------------------
extern "C" void kernel_launch(void* const* d_in, const int* in_sizes, int n_in,
                              void* d_out, int out_size, void* d_ws, size_t ws_size,
                              hipStream_t stream) {
  (void)in_sizes; (void)n_in; (void)out_size; (void)ws_size;
  const float* x  = (const float*)d_in[0];
  const float* y  = (const float*)d_in[1];
  const float* Wq = (const float*)d_in[2];
  const float* bq = (const float*)d_in[3];
  const float* Wk = (const float*)d_in[4];
  const float* bk = (const float*)d_in[5];
  const float* Wv = (const float*)d_in[6];
  const float* bv = (const float*)d_in[7];
  const float* Wo = (const float*)d_in[8];
  const float* bo = (const float*)d_in[9];

  char* ws = (char*)d_ws;
  short* Qb = (short*)(ws);
  short* Kb = (short*)(ws + 6291456);
  short* Vt = (short*)(ws + 12582912);
  short* Xn = (short*)(ws + 18874368);
  float* ctx = (float*)(ws + 25165824);

  const float SC = 0.07362233f;  // (1/sqrt(384)) * log2(e), folded into Q
  dim3 blk(256);
  gemm_nt<1, 0, 1><<<dim3(64, 3), blk, 0, stream>>>(x, Wq, bq, Qb, 8192, 384, 384, SC);
  gemm_nt<1, 0, 1><<<dim3(64, 3), blk, 0, stream>>>(y, Wk, bk, Kb, 8192, 384, 384, 1.0f);
  gemm_nt<0, 0, 1><<<dim3(3, 64), blk, 0, stream>>>(Wv, y, bv, Vt, 384, 8192, 384, 1.0f);
  flash_attn<<<dim3(512), blk, 0, stream>>>(Qb, Kb, Vt, ctx);
  combine_norm<<<dim3(2048), blk, 0, stream>>>(ctx, x, Xn);
  gemm_nt<1, 1, 0><<<dim3(64, 3), blk, 0, stream>>>(Xn, Wo, bo, (float*)d_out, 8192, 384, 384, 1.0f);
}

// Round 3
// 363.490 us; speedup vs baseline: 1.1760x; 1.1760x over previous
//
#include <hip/hip_runtime.h>
#include <stdint.h>

// ---------------------------------------------------------------------------
// Fused: Q=x@Wq^T+bq; K=y@Wk^T+bk; V=y@Wv^T+bv; ctx=softmax(QK^T/sqrt(384))@V
//        out = (x + ctx/||ctx||_row) @ Wo^T + bo        (N=M=8192, D=384)
// softmax: no max-subtraction needed (logit sigma ~0.33); denominator cancels
// under F.normalize. Scale*log2e folded into Q projection -> P = exp2(S).
// flash v3 = v2 minus register spill: single S chain (-16 regs), fused
// exp2/cvt_pk (-14), hoisted staging offsets, waves_per_eu(2,2) pinning the
// allocator at 256 total regs (r2 clamped arch VGPR to 128 and spilled:
// +18MB scratch writes, 30ms first dispatch).
// ws layout: Qb bf16[8192,384]@0; Kb@6291456; Vt bf16[384,8192]@12582912;
//            Xn bf16[8192,384]@18874368; ctx f32[4][8192,384]@25165824
// ---------------------------------------------------------------------------

typedef __attribute__((ext_vector_type(8))) short bf16x8;
typedef __attribute__((ext_vector_type(4))) float f32x4;
typedef __attribute__((ext_vector_type(16))) float f32x16;

#define DEV static __device__ __forceinline__

DEV short f2bf(float f) {
  uint32_t u = __builtin_bit_cast(uint32_t, f);
  u += 0x7fffu + ((u >> 16) & 1u);
  return (short)(u >> 16);
}
DEV uint32_t pack2(float a, float b) {
  return (uint32_t)(uint16_t)f2bf(a) | ((uint32_t)(uint16_t)f2bf(b) << 16);
}
DEV unsigned cvt_pk(float lo, float hi) {
  unsigned r;
  asm("v_cvt_pk_bf16_f32 %0, %1, %2" : "=v"(r) : "v"(lo), "v"(hi));
  return r;
}
DEV void pl32swap(unsigned& a, unsigned& b) {
  asm volatile("v_permlane32_swap_b32 %0, %1" : "+v"(a), "+v"(b));
}
DEV void gload16(const void* g, void* l) {
  __builtin_amdgcn_global_load_lds(
      (const __attribute__((address_space(1))) unsigned*)g,
      (__attribute__((address_space(3))) unsigned*)l, 16, 0, 0);
}

// ---------------------------------------------------------------------------
// Generic GEMM-NT: C[m,n] = (sum_k A[m,k]*B[n,k] + bias) * scale
// ---------------------------------------------------------------------------
template <int BIAS_ON_N, int OUT_F32, int A_F32>
__global__ __launch_bounds__(256) void gemm_nt(
    const void* __restrict__ Aptr, const float* __restrict__ B,
    const float* __restrict__ bias, void* __restrict__ Cptr,
    int M, int N, int K, float scale) {
  __shared__ char As[128 * 128];
  __shared__ char Bs[128 * 128];
  const int tid = threadIdx.x;
  const int l = tid & 63, w = tid >> 6;
  const int lq = l & 15, lk = l >> 4;
  const int m0 = blockIdx.x * 128, n0 = blockIdx.y * 128;
  const int wr = (w >> 1) * 64, wc = (w & 1) * 64;
  f32x4 acc[4][4] = {};

  for (int k0 = 0; k0 < K; k0 += 64) {
    if (A_F32) {
      const float* A = (const float*)Aptr;
#pragma unroll
      for (int i = 0; i < 8; i++) {
        int c = tid + i * 256;
        int row = c >> 4, col = (c & 15) * 4;
        f32x4 v = *(const f32x4*)(A + (size_t)(m0 + row) * K + k0 + col);
        uint32_t lo = pack2(v.x, v.y), hi = pack2(v.z, v.w);
        int off = (row * 128 + col * 2) ^ ((row & 7) << 4);
        *(uint32_t*)(As + off) = lo;
        *(uint32_t*)(As + off + 4) = hi;
      }
    } else {
      const short* A = (const short*)Aptr;
#pragma unroll
      for (int i = 0; i < 4; i++) {
        int c = tid + i * 256;
        int row = c >> 3, col = (c & 7) * 8;
        uint4 v = *(const uint4*)(A + (size_t)(m0 + row) * K + k0 + col);
        int off = (row * 128 + col * 2) ^ ((row & 7) << 4);
        *(uint4*)(As + off) = v;
      }
    }
#pragma unroll
    for (int i = 0; i < 8; i++) {
      int c = tid + i * 256;
      int row = c >> 4, col = (c & 15) * 4;
      f32x4 v = *(const f32x4*)(B + (size_t)(n0 + row) * K + k0 + col);
      uint32_t lo = pack2(v.x, v.y), hi = pack2(v.z, v.w);
      int off = (row * 128 + col * 2) ^ ((row & 7) << 4);
      *(uint32_t*)(Bs + off) = lo;
      *(uint32_t*)(Bs + off + 4) = hi;
    }
    __syncthreads();
#pragma unroll
    for (int ks = 0; ks < 2; ks++) {
      bf16x8 af[4], bfr[4];
#pragma unroll
      for (int m = 0; m < 4; m++) {
        int row = wr + m * 16 + lq;
        af[m] = *(const bf16x8*)(As + ((row * 128 + ks * 64 + lk * 16) ^ ((row & 7) << 4)));
      }
#pragma unroll
      for (int n = 0; n < 4; n++) {
        int row = wc + n * 16 + lq;
        bfr[n] = *(const bf16x8*)(Bs + ((row * 128 + ks * 64 + lk * 16) ^ ((row & 7) << 4)));
      }
#pragma unroll
      for (int m = 0; m < 4; m++)
#pragma unroll
        for (int n = 0; n < 4; n++)
          acc[m][n] = __builtin_amdgcn_mfma_f32_16x16x32_bf16(af[m], bfr[n], acc[m][n], 0, 0, 0);
    }
    __syncthreads();
  }
#pragma unroll
  for (int m = 0; m < 4; m++) {
    int mg = m0 + wr + m * 16 + lk * 4;
#pragma unroll
    for (int n = 0; n < 4; n++) {
      int ng = n0 + wc + n * 16 + lq;
#pragma unroll
      for (int r = 0; r < 4; r++) {
        float v = (acc[m][n][r] + (BIAS_ON_N ? bias[ng] : bias[mg + r])) * scale;
        if (OUT_F32)
          ((float*)Cptr)[(size_t)(mg + r) * N + ng] = v;
        else
          ((short*)Cptr)[(size_t)(mg + r) * N + ng] = f2bf(v);
      }
    }
  }
}

// ---------------------------------------------------------------------------
// Flash numerator v3. Grid 512 = 128 q-tiles x 4 splits (split = bid&3, XCD-
// aligned). Block 256 = 4 waves: wave w = (q-group w>>1, d-half w&1).
// S^T[32kv x 32q] = single-chain mfma(K,Q); P in regs (cvt_pk + permlane32);
// ctx^T += mfma(V,P^T). K dbuf + V sbuf via global_load_lds (pre-swizzled
// src), raw s_barrier + counted vmcnt(6). Registers: qf 96 + acc 96 + S 16
// + ~25 misc = ~241 <= 256 (waves_per_eu(2,2) pins budget; r2 spilled here).
// ---------------------------------------------------------------------------
#define ITERS 64

__global__ __launch_bounds__(256)
__attribute__((amdgpu_waves_per_eu(2, 2))) void flash_attn(
    const short* __restrict__ Qb, const short* __restrict__ Kb,
    const short* __restrict__ Vt, float* __restrict__ ctx_part) {
  __shared__ char Ks[2][24576];
  __shared__ char Vs[24576];
  const int tid = threadIdx.x, l = tid & 63, w = tid >> 6;
  const int l31 = l & 31, h = l >> 5;
  const int qh = w >> 1, dh = w & 1;
  const int sp = blockIdx.x & 3, qt = blockIdx.x >> 2;
  const int q0 = qt * 64 + qh * 32;
  const int kvbase = sp * 2048;

  // hoisted per-lane staging offsets (loop-invariant)
  int koff[6], voff[6];
#pragma unroll
  for (int i = 0; i < 6; i++) {
    int d = (w * 6 + i) * 1024 + l * 16;
    int krow = d / 768, kc = d - krow * 768;
    koff[i] = krow * 768 + (kc ^ ((krow & 7) << 4));
    int vrow = d >> 6, vc = d & 63;
    voff[i] = vrow * 16384 + (vc ^ (((vrow >> 1) & 3) << 4));
  }
  const int ldsoff = w * 6144 + 0;  // chunk base (w*6+i)*1024

  // Q B-frags resident: col q = q0+l31, k = s*16 + h*8 + j  (96 VGPR)
  bf16x8 qf[24];
  {
    const short* qrow = Qb + (size_t)(q0 + l31) * 384 + h * 8;
#pragma unroll
    for (int s = 0; s < 24; s++) qf[s] = *(const bf16x8*)(qrow + s * 16);
  }
  asm volatile("s_waitcnt vmcnt(0)" ::: "memory");

  // stage K(0) into Ks[0]
  {
    const char* kb = (const char*)Kb + (size_t)kvbase * 768;
#pragma unroll
    for (int i = 0; i < 6; i++)
      gload16(kb + koff[i], (char*)Ks[0] + ldsoff + i * 1024);
  }

  f32x16 acc[6] = {};

#pragma unroll 1
  for (int t = 0; t < ITERS; t++) {
    const char* Kc = Ks[t & 1];
    // ---- stage V(t) (Vbuf free since barrier C of t-1) ----
    {
      const char* vb = (const char*)Vt + (size_t)(kvbase + t * 32) * 2;
#pragma unroll
      for (int i = 0; i < 6; i++)
        gload16(vb + voff[i], Vs + ldsoff + i * 1024);
    }
    asm volatile("s_waitcnt vmcnt(6)" ::: "memory");  // K(t) landed, V(t) in flight
    __builtin_amdgcn_s_barrier();                     // A: K(t) visible block-wide

    // ---- S^T = K Q^T : single accumulation chain (16 regs) ----
    f32x16 S = {};
    const char* kcb = Kc + l31 * 768;
    const int swzk = (l31 & 7) << 4;
    __builtin_amdgcn_s_setprio(1);
#pragma unroll
    for (int s = 0; s < 24; s++) {
      bf16x8 k0 = *(const bf16x8*)(kcb + ((s * 32 + h * 16) ^ swzk));
      S = __builtin_amdgcn_mfma_f32_32x32x16_bf16(k0, qf[s], S, 0, 0, 0);
    }
    __builtin_amdgcn_s_setprio(0);

    // ---- stage K(t+1) into other buffer (overlaps softmax VALU) ----
    if (t < ITERS - 1) {
      const char* kb = (const char*)Kb + (size_t)(kvbase + (t + 1) * 32) * 768;
      char* Kn = (char*)Ks[(t & 1) ^ 1];
#pragma unroll
      for (int i = 0; i < 6; i++)
        gload16(kb + koff[i], Kn + ldsoff + i * 1024);
    }

    // ---- P = exp2(S^T) -> bf16 frags, fused (2 float temps live) ----
    unsigned a0 = cvt_pk(__builtin_amdgcn_exp2f(S[0]), __builtin_amdgcn_exp2f(S[1]));
    unsigned a1 = cvt_pk(__builtin_amdgcn_exp2f(S[2]), __builtin_amdgcn_exp2f(S[3]));
    unsigned a2 = cvt_pk(__builtin_amdgcn_exp2f(S[4]), __builtin_amdgcn_exp2f(S[5]));
    unsigned a3 = cvt_pk(__builtin_amdgcn_exp2f(S[6]), __builtin_amdgcn_exp2f(S[7]));
    pl32swap(a0, a2); pl32swap(a1, a3);
    uint4 pw0 = {a0, a1, a2, a3};
    bf16x8 pf0 = __builtin_bit_cast(bf16x8, pw0);
    unsigned b0 = cvt_pk(__builtin_amdgcn_exp2f(S[8]), __builtin_amdgcn_exp2f(S[9]));
    unsigned b1 = cvt_pk(__builtin_amdgcn_exp2f(S[10]), __builtin_amdgcn_exp2f(S[11]));
    unsigned b2 = cvt_pk(__builtin_amdgcn_exp2f(S[12]), __builtin_amdgcn_exp2f(S[13]));
    unsigned b3 = cvt_pk(__builtin_amdgcn_exp2f(S[14]), __builtin_amdgcn_exp2f(S[15]));
    pl32swap(b0, b2); pl32swap(b1, b3);
    uint4 pw1 = {b0, b1, b2, b3};
    bf16x8 pf1 = __builtin_bit_cast(bf16x8, pw1);

    if (t < ITERS - 1)
      asm volatile("s_waitcnt vmcnt(6)" ::: "memory");  // V(t) landed, K(t+1) in flight
    else
      asm volatile("s_waitcnt vmcnt(0)" ::: "memory");
    __builtin_amdgcn_s_barrier();                       // B: V(t) visible block-wide

    // ---- ctx^T += V^T P^T  (6 d-frags x 2 kv-steps) ----
    const char* vsb = Vs + (dh * 192 + l31) * 64;
    __builtin_amdgcn_s_setprio(1);
#pragma unroll
    for (int nf = 0; nf < 6; nf++) {
      int vr = dh * 192 + nf * 32 + l31;
      int swz = ((vr >> 1) & 3) << 4;
      bf16x8 v0 = *(const bf16x8*)(vsb + nf * 2048 + ((h * 16) ^ swz));
      bf16x8 v1 = *(const bf16x8*)(vsb + nf * 2048 + ((32 + h * 16) ^ swz));
      acc[nf] = __builtin_amdgcn_mfma_f32_32x32x16_bf16(v0, pf0, acc[nf], 0, 0, 0);
      acc[nf] = __builtin_amdgcn_mfma_f32_32x32x16_bf16(v1, pf1, acc[nf], 0, 0, 0);
    }
    __builtin_amdgcn_s_setprio(0);
    __builtin_amdgcn_s_barrier();  // C: V consumption done -> Vbuf reusable
  }

  // ---- epilogue: ctx^T frags -> ctx_part[sp][q][d]; lane owns one q row ----
  float* outp = ctx_part + (size_t)sp * 8192 * 384 + (size_t)(q0 + l31) * 384;
#pragma unroll
  for (int nf = 0; nf < 6; nf++) {
#pragma unroll
    for (int qd = 0; qd < 4; qd++) {
      f32x4 v = {acc[nf][qd * 4 + 0], acc[nf][qd * 4 + 1],
                 acc[nf][qd * 4 + 2], acc[nf][qd * 4 + 3]};
      *(f32x4*)(outp + dh * 192 + nf * 32 + qd * 8 + h * 4) = v;
    }
  }
}

// ---------------------------------------------------------------------------
// Combine: ctx = sum splits; Xn = bf16(x + ctx/||ctx||)  (softmax denominator
// cancelled analytically). One wave per q row.
// ---------------------------------------------------------------------------
__global__ __launch_bounds__(256) void combine_norm(
    const float* __restrict__ ctx_part, const float* __restrict__ x,
    short* __restrict__ Xn) {
  const int l = threadIdx.x & 63, w = threadIdx.x >> 6;
  const int q = blockIdx.x * 4 + w;
  const size_t SLAB = (size_t)8192 * 384;
  float v[6];
  float ss = 0.f;
#pragma unroll
  for (int i = 0; i < 6; i++) {
    size_t off = (size_t)q * 384 + i * 64 + l;
    float s = ctx_part[off] + ctx_part[off + SLAB] + ctx_part[off + 2 * SLAB] +
              ctx_part[off + 3 * SLAB];
    v[i] = s;
    ss += s * s;
  }
#pragma unroll
  for (int m = 1; m <= 32; m <<= 1) ss += __shfl_xor(ss, m);
  float inv = 1.0f / fmaxf(sqrtf(ss), 1e-12f);
#pragma unroll
  for (int i = 0; i < 6; i++) {
    size_t off = (size_t)q * 384 + i * 64 + l;
    Xn[off] = f2bf(x[off] + v[i] * inv);
  }
}

// ---------------------------------------------------------------------------
extern "C" void kernel_launch(void* const* d_in, const int* in_sizes, int n_in,
                              void* d_out, int out_size, void* d_ws, size_t ws_size,
                              hipStream_t stream) {
  (void)in_sizes; (void)n_in; (void)out_size; (void)ws_size;
  const float* x  = (const float*)d_in[0];
  const float* y  = (const float*)d_in[1];
  const float* Wq = (const float*)d_in[2];
  const float* bq = (const float*)d_in[3];
  const float* Wk = (const float*)d_in[4];
  const float* bk = (const float*)d_in[5];
  const float* Wv = (const float*)d_in[6];
  const float* bv = (const float*)d_in[7];
  const float* Wo = (const float*)d_in[8];
  const float* bo = (const float*)d_in[9];

  char* ws = (char*)d_ws;
  short* Qb = (short*)(ws);
  short* Kb = (short*)(ws + 6291456);
  short* Vt = (short*)(ws + 12582912);
  short* Xn = (short*)(ws + 18874368);
  float* ctx = (float*)(ws + 25165824);

  const float SC = 0.07362233f;  // (1/sqrt(384)) * log2(e), folded into Q
  dim3 blk(256);
  gemm_nt<1, 0, 1><<<dim3(64, 3), blk, 0, stream>>>(x, Wq, bq, Qb, 8192, 384, 384, SC);
  gemm_nt<1, 0, 1><<<dim3(64, 3), blk, 0, stream>>>(y, Wk, bk, Kb, 8192, 384, 384, 1.0f);
  gemm_nt<0, 0, 1><<<dim3(3, 64), blk, 0, stream>>>(Wv, y, bv, Vt, 384, 8192, 384, 1.0f);
  flash_attn<<<dim3(512), blk, 0, stream>>>(Qb, Kb, Vt, ctx);
  combine_norm<<<dim3(2048), blk, 0, stream>>>(ctx, x, Xn);
  gemm_nt<1, 1, 0><<<dim3(64, 3), blk, 0, stream>>>(Xn, Wo, bo, (float*)d_out, 8192, 384, 384, 1.0f);
}

// Round 4
// 302.001 us; speedup vs baseline: 1.4154x; 1.2036x over previous
//
#include <hip/hip_runtime.h>
#include <stdint.h>

// ---------------------------------------------------------------------------
// Fused: Q=x@Wq^T+bq; K=y@Wk^T+bk; V=y@Wv^T+bv; ctx=softmax(QK^T/sqrt(384))@V
//        out = (x + ctx/||ctx||_row) @ Wo^T + bo        (N=M=8192, D=384)
// softmax: no max-subtraction needed (logit sigma ~0.33); denominator cancels
// under F.normalize. Scale*log2e folded into Q projection -> P = exp2(S).
// flash v4: 8 waves / 128q per block, grid 256 (1 block/CU, split XCD-pinned).
// QK deduplicated: wave (qh,dh) computes S^T only on tiles with dh==t&1 and
// shares P with its partner via a 2KB/qh LDS dbuf -> K LDS reads halve, QK
// MFMAs halve. Pipeline PV(t-1) || QK(t): K dbuf + V tribuf + P dbuf gives
// ONE __syncthreads per tile (v3 had 3 barriers). LDS 136KB/block.
// ws layout: Qb bf16[8192,384]@0; Kb@6291456; Vt bf16[384,8192]@12582912;
//            Xn bf16[8192,384]@18874368; ctx f32[4][8192,384]@25165824
// ---------------------------------------------------------------------------

typedef __attribute__((ext_vector_type(8))) short bf16x8;
typedef __attribute__((ext_vector_type(4))) float f32x4;
typedef __attribute__((ext_vector_type(16))) float f32x16;

#define DEV static __device__ __forceinline__

DEV short f2bf(float f) {
  uint32_t u = __builtin_bit_cast(uint32_t, f);
  u += 0x7fffu + ((u >> 16) & 1u);
  return (short)(u >> 16);
}
DEV uint32_t pack2(float a, float b) {
  return (uint32_t)(uint16_t)f2bf(a) | ((uint32_t)(uint16_t)f2bf(b) << 16);
}
DEV unsigned cvt_pk(float lo, float hi) {
  unsigned r;
  asm("v_cvt_pk_bf16_f32 %0, %1, %2" : "=v"(r) : "v"(lo), "v"(hi));
  return r;
}
DEV void pl32swap(unsigned& a, unsigned& b) {
  asm volatile("v_permlane32_swap_b32 %0, %1" : "+v"(a), "+v"(b));
}
DEV void gload16(const void* g, void* l) {
  __builtin_amdgcn_global_load_lds(
      (const __attribute__((address_space(1))) unsigned*)g,
      (__attribute__((address_space(3))) unsigned*)l, 16, 0, 0);
}

// ---------------------------------------------------------------------------
// Generic GEMM-NT: C[m,n] = (sum_k A[m,k]*B[n,k] + bias) * scale
// ---------------------------------------------------------------------------
template <int BIAS_ON_N, int OUT_F32, int A_F32>
__global__ __launch_bounds__(256) void gemm_nt(
    const void* __restrict__ Aptr, const float* __restrict__ B,
    const float* __restrict__ bias, void* __restrict__ Cptr,
    int M, int N, int K, float scale) {
  __shared__ char As[128 * 128];
  __shared__ char Bs[128 * 128];
  const int tid = threadIdx.x;
  const int l = tid & 63, w = tid >> 6;
  const int lq = l & 15, lk = l >> 4;
  const int m0 = blockIdx.x * 128, n0 = blockIdx.y * 128;
  const int wr = (w >> 1) * 64, wc = (w & 1) * 64;
  f32x4 acc[4][4] = {};

  for (int k0 = 0; k0 < K; k0 += 64) {
    if (A_F32) {
      const float* A = (const float*)Aptr;
#pragma unroll
      for (int i = 0; i < 8; i++) {
        int c = tid + i * 256;
        int row = c >> 4, col = (c & 15) * 4;
        f32x4 v = *(const f32x4*)(A + (size_t)(m0 + row) * K + k0 + col);
        uint32_t lo = pack2(v.x, v.y), hi = pack2(v.z, v.w);
        int off = (row * 128 + col * 2) ^ ((row & 7) << 4);
        *(uint32_t*)(As + off) = lo;
        *(uint32_t*)(As + off + 4) = hi;
      }
    } else {
      const short* A = (const short*)Aptr;
#pragma unroll
      for (int i = 0; i < 4; i++) {
        int c = tid + i * 256;
        int row = c >> 3, col = (c & 7) * 8;
        uint4 v = *(const uint4*)(A + (size_t)(m0 + row) * K + k0 + col);
        int off = (row * 128 + col * 2) ^ ((row & 7) << 4);
        *(uint4*)(As + off) = v;
      }
    }
#pragma unroll
    for (int i = 0; i < 8; i++) {
      int c = tid + i * 256;
      int row = c >> 4, col = (c & 15) * 4;
      f32x4 v = *(const f32x4*)(B + (size_t)(n0 + row) * K + k0 + col);
      uint32_t lo = pack2(v.x, v.y), hi = pack2(v.z, v.w);
      int off = (row * 128 + col * 2) ^ ((row & 7) << 4);
      *(uint32_t*)(Bs + off) = lo;
      *(uint32_t*)(Bs + off + 4) = hi;
    }
    __syncthreads();
#pragma unroll
    for (int ks = 0; ks < 2; ks++) {
      bf16x8 af[4], bfr[4];
#pragma unroll
      for (int m = 0; m < 4; m++) {
        int row = wr + m * 16 + lq;
        af[m] = *(const bf16x8*)(As + ((row * 128 + ks * 64 + lk * 16) ^ ((row & 7) << 4)));
      }
#pragma unroll
      for (int n = 0; n < 4; n++) {
        int row = wc + n * 16 + lq;
        bfr[n] = *(const bf16x8*)(Bs + ((row * 128 + ks * 64 + lk * 16) ^ ((row & 7) << 4)));
      }
#pragma unroll
      for (int m = 0; m < 4; m++)
#pragma unroll
        for (int n = 0; n < 4; n++)
          acc[m][n] = __builtin_amdgcn_mfma_f32_16x16x32_bf16(af[m], bfr[n], acc[m][n], 0, 0, 0);
    }
    __syncthreads();
  }
#pragma unroll
  for (int m = 0; m < 4; m++) {
    int mg = m0 + wr + m * 16 + lk * 4;
#pragma unroll
    for (int n = 0; n < 4; n++) {
      int ng = n0 + wc + n * 16 + lq;
#pragma unroll
      for (int r = 0; r < 4; r++) {
        float v = (acc[m][n][r] + (BIAS_ON_N ? bias[ng] : bias[mg + r])) * scale;
        if (OUT_F32)
          ((float*)Cptr)[(size_t)(mg + r) * N + ng] = v;
        else
          ((short*)Cptr)[(size_t)(mg + r) * N + ng] = f2bf(v);
      }
    }
  }
}

// ---------------------------------------------------------------------------
// Flash numerator v4. Grid 256 = 64 q-tiles x 4 splits (split=bid&3: XCD x
// always serves split x&3 -> split K/V (3MB) L2-resident per XCD).
// Block 512 thr = 8 waves: wave w -> (qh=w&3, dh=w>>2), owns 32q x 192d.
// Tile = 32 kv. Wave does QK(t) only when dh==t&1 (K read once, not twice);
// P[32kv x 32q] bf16 crosses to partner via LDS dbuf (identity lane map).
// All waves do PV(t-1) each tile. One __syncthreads per tile.
// ---------------------------------------------------------------------------
#define ITERS 64

__global__ __launch_bounds__(512)
__attribute__((amdgpu_waves_per_eu(2, 2))) void flash_attn(
    const short* __restrict__ Qb, const short* __restrict__ Kb,
    const short* __restrict__ Vt, float* __restrict__ ctx_part) {
  __shared__ char Ks[2][24576];      // [32 kv][768B] swz (row&7)<<4, dbuf
  __shared__ char Vs[3][24576];      // [384 d][64B] swz ((row>>1)&3)<<4, tribuf
  __shared__ char Ps[2][4][2048];    // per qh: [2 s][32 q][16 kv] bf16, dbuf
  const int tid = threadIdx.x, l = tid & 63, w = tid >> 6;
  const int l31 = l & 31, h = l >> 5;
  const int qh = w & 3, dh = w >> 2;
  const int sp = blockIdx.x & 3, qt = blockIdx.x >> 2;
  const int q0 = qt * 128 + qh * 32;
  const int kvbase = sp * 2048;
  const int pswz = ((l31 >> 2) & 7) << 4;
  const int poff = (l31 * 32 + h * 16) ^ pswz;  // P byte offset (write==read)

  // staging: waves 0-3 stage K (24 chunks), waves 4-7 stage V (24 chunks)
  int off6[6];
  const int cb = (w & 3) * 6144;  // LDS chunk base within tile buffer
  if (dh == 0) {
#pragma unroll
    for (int i = 0; i < 6; i++) {
      int d = cb + i * 1024 + l * 16;
      int krow = d / 768, kc = d - krow * 768;
      off6[i] = krow * 768 + (kc ^ ((krow & 7) << 4));
    }
  } else {
#pragma unroll
    for (int i = 0; i < 6; i++) {
      int d = cb + i * 1024 + l * 16;
      int vrow = d >> 6, vc = d & 63;
      off6[i] = vrow * 16384 + (vc ^ (((vrow >> 1) & 3) << 4));
    }
  }

  // Q B-frags resident: col q = q0+l31, k = s*16 + h*8 + j  (96 VGPR)
  bf16x8 qf[24];
  {
    const short* qrow = Qb + (size_t)(q0 + l31) * 384 + h * 8;
#pragma unroll
    for (int s = 0; s < 24; s++) qf[s] = *(const bf16x8*)(qrow + s * 16);
  }

  // stage tile 0
  if (dh == 0) {
    const char* kb = (const char*)Kb + (size_t)kvbase * 768;
#pragma unroll
    for (int i = 0; i < 6; i++) gload16(kb + off6[i], Ks[0] + cb + i * 1024);
  } else {
    const char* vb = (const char*)Vt + (size_t)kvbase * 2;
#pragma unroll
    for (int i = 0; i < 6; i++) gload16(vb + off6[i], Vs[0] + cb + i * 1024);
  }

  f32x16 acc[6] = {};
  __syncthreads();  // tile 0 staged

#pragma unroll 1
  for (int t = 0; t < ITERS; t++) {
    // ---- issue stage(t+1): lands anytime this tile (slots unused by readers)
    if (t < ITERS - 1) {
      int kv0 = kvbase + (t + 1) * 32;
      if (dh == 0) {
        const char* kb = (const char*)Kb + (size_t)kv0 * 768;
        char* dst = Ks[(t + 1) & 1] + cb;
#pragma unroll
        for (int i = 0; i < 6; i++) gload16(kb + off6[i], dst + i * 1024);
      } else {
        const char* vb = (const char*)Vt + (size_t)kv0 * 2;
        char* dst = Vs[(t + 1) % 3] + cb;
#pragma unroll
        for (int i = 0; i < 6; i++) gload16(vb + off6[i], dst + i * 1024);
      }
    }

    // ---- QK(t) duty: S^T = K Q^T, P -> LDS (my qh's slot) ----
    if (dh == (t & 1)) {
      f32x16 S = {};
      const char* kcb = Ks[t & 1] + l31 * 768;
      const int swzk = (l31 & 7) << 4;
      __builtin_amdgcn_s_setprio(1);
#pragma unroll
      for (int s = 0; s < 24; s++) {
        bf16x8 k0 = *(const bf16x8*)(kcb + ((s * 32 + h * 16) ^ swzk));
        S = __builtin_amdgcn_mfma_f32_32x32x16_bf16(k0, qf[s], S, 0, 0, 0);
      }
      __builtin_amdgcn_s_setprio(0);
      unsigned a0 = cvt_pk(__builtin_amdgcn_exp2f(S[0]), __builtin_amdgcn_exp2f(S[1]));
      unsigned a1 = cvt_pk(__builtin_amdgcn_exp2f(S[2]), __builtin_amdgcn_exp2f(S[3]));
      unsigned a2 = cvt_pk(__builtin_amdgcn_exp2f(S[4]), __builtin_amdgcn_exp2f(S[5]));
      unsigned a3 = cvt_pk(__builtin_amdgcn_exp2f(S[6]), __builtin_amdgcn_exp2f(S[7]));
      pl32swap(a0, a2); pl32swap(a1, a3);
      uint4 pw0 = {a0, a1, a2, a3};
      unsigned b0 = cvt_pk(__builtin_amdgcn_exp2f(S[8]), __builtin_amdgcn_exp2f(S[9]));
      unsigned b1 = cvt_pk(__builtin_amdgcn_exp2f(S[10]), __builtin_amdgcn_exp2f(S[11]));
      unsigned b2 = cvt_pk(__builtin_amdgcn_exp2f(S[12]), __builtin_amdgcn_exp2f(S[13]));
      unsigned b3 = cvt_pk(__builtin_amdgcn_exp2f(S[14]), __builtin_amdgcn_exp2f(S[15]));
      pl32swap(b0, b2); pl32swap(b1, b3);
      uint4 pw1 = {b0, b1, b2, b3};
      char* pwb = Ps[t & 1][qh];
      *(uint4*)(pwb + poff) = pw0;
      *(uint4*)(pwb + 1024 + poff) = pw1;
    }

    // ---- PV(t-1): all waves, own (qh,dh) partition ----
    if (t > 0) {
      const char* pb = Ps[(t - 1) & 1][qh];
      bf16x8 pf0 = *(const bf16x8*)(pb + poff);
      bf16x8 pf1 = *(const bf16x8*)(pb + 1024 + poff);
      const char* vb = Vs[(t - 1) % 3];
      __builtin_amdgcn_s_setprio(1);
#pragma unroll
      for (int nf = 0; nf < 6; nf++) {
        int vr = dh * 192 + nf * 32 + l31;
        int swz = ((vr >> 1) & 3) << 4;
        const char* vrow = vb + vr * 64;
        bf16x8 v0 = *(const bf16x8*)(vrow + ((h * 16) ^ swz));
        bf16x8 v1 = *(const bf16x8*)(vrow + ((32 + h * 16) ^ swz));
        acc[nf] = __builtin_amdgcn_mfma_f32_32x32x16_bf16(v0, pf0, acc[nf], 0, 0, 0);
        acc[nf] = __builtin_amdgcn_mfma_f32_32x32x16_bf16(v1, pf1, acc[nf], 0, 0, 0);
      }
      __builtin_amdgcn_s_setprio(0);
    }
    __syncthreads();  // drains DMA (vmcnt) + P writes (lgkm); one barrier/tile
  }

  // ---- tail: PV(63) ----
  {
    const char* pb = Ps[(ITERS - 1) & 1][qh];
    bf16x8 pf0 = *(const bf16x8*)(pb + poff);
    bf16x8 pf1 = *(const bf16x8*)(pb + 1024 + poff);
    const char* vb = Vs[(ITERS - 1) % 3];
#pragma unroll
    for (int nf = 0; nf < 6; nf++) {
      int vr = dh * 192 + nf * 32 + l31;
      int swz = ((vr >> 1) & 3) << 4;
      const char* vrow = vb + vr * 64;
      bf16x8 v0 = *(const bf16x8*)(vrow + ((h * 16) ^ swz));
      bf16x8 v1 = *(const bf16x8*)(vrow + ((32 + h * 16) ^ swz));
      acc[nf] = __builtin_amdgcn_mfma_f32_32x32x16_bf16(v0, pf0, acc[nf], 0, 0, 0);
      acc[nf] = __builtin_amdgcn_mfma_f32_32x32x16_bf16(v1, pf1, acc[nf], 0, 0, 0);
    }
  }

  // ---- epilogue: ctx^T frags -> ctx_part[sp][q][d]; lane owns one q row ----
  float* outp = ctx_part + (size_t)sp * 8192 * 384 + (size_t)(q0 + l31) * 384;
#pragma unroll
  for (int nf = 0; nf < 6; nf++) {
#pragma unroll
    for (int qd = 0; qd < 4; qd++) {
      f32x4 v = {acc[nf][qd * 4 + 0], acc[nf][qd * 4 + 1],
                 acc[nf][qd * 4 + 2], acc[nf][qd * 4 + 3]};
      *(f32x4*)(outp + dh * 192 + nf * 32 + qd * 8 + h * 4) = v;
    }
  }
}

// ---------------------------------------------------------------------------
// Combine: ctx = sum splits; Xn = bf16(x + ctx/||ctx||)  (softmax denominator
// cancelled analytically). One wave per q row.
// ---------------------------------------------------------------------------
__global__ __launch_bounds__(256) void combine_norm(
    const float* __restrict__ ctx_part, const float* __restrict__ x,
    short* __restrict__ Xn) {
  const int l = threadIdx.x & 63, w = threadIdx.x >> 6;
  const int q = blockIdx.x * 4 + w;
  const size_t SLAB = (size_t)8192 * 384;
  float v[6];
  float ss = 0.f;
#pragma unroll
  for (int i = 0; i < 6; i++) {
    size_t off = (size_t)q * 384 + i * 64 + l;
    float s = ctx_part[off] + ctx_part[off + SLAB] + ctx_part[off + 2 * SLAB] +
              ctx_part[off + 3 * SLAB];
    v[i] = s;
    ss += s * s;
  }
#pragma unroll
  for (int m = 1; m <= 32; m <<= 1) ss += __shfl_xor(ss, m);
  float inv = 1.0f / fmaxf(sqrtf(ss), 1e-12f);
#pragma unroll
  for (int i = 0; i < 6; i++) {
    size_t off = (size_t)q * 384 + i * 64 + l;
    Xn[off] = f2bf(x[off] + v[i] * inv);
  }
}

// ---------------------------------------------------------------------------
extern "C" void kernel_launch(void* const* d_in, const int* in_sizes, int n_in,
                              void* d_out, int out_size, void* d_ws, size_t ws_size,
                              hipStream_t stream) {
  (void)in_sizes; (void)n_in; (void)out_size; (void)ws_size;
  const float* x  = (const float*)d_in[0];
  const float* y  = (const float*)d_in[1];
  const float* Wq = (const float*)d_in[2];
  const float* bq = (const float*)d_in[3];
  const float* Wk = (const float*)d_in[4];
  const float* bk = (const float*)d_in[5];
  const float* Wv = (const float*)d_in[6];
  const float* bv = (const float*)d_in[7];
  const float* Wo = (const float*)d_in[8];
  const float* bo = (const float*)d_in[9];

  char* ws = (char*)d_ws;
  short* Qb = (short*)(ws);
  short* Kb = (short*)(ws + 6291456);
  short* Vt = (short*)(ws + 12582912);
  short* Xn = (short*)(ws + 18874368);
  float* ctx = (float*)(ws + 25165824);

  const float SC = 0.07362233f;  // (1/sqrt(384)) * log2(e), folded into Q
  dim3 blk(256);
  gemm_nt<1, 0, 1><<<dim3(64, 3), blk, 0, stream>>>(x, Wq, bq, Qb, 8192, 384, 384, SC);
  gemm_nt<1, 0, 1><<<dim3(64, 3), blk, 0, stream>>>(y, Wk, bk, Kb, 8192, 384, 384, 1.0f);
  gemm_nt<0, 0, 1><<<dim3(3, 64), blk, 0, stream>>>(Wv, y, bv, Vt, 384, 8192, 384, 1.0f);
  flash_attn<<<dim3(256), dim3(512), 0, stream>>>(Qb, Kb, Vt, ctx);
  combine_norm<<<dim3(2048), blk, 0, stream>>>(ctx, x, Xn);
  gemm_nt<1, 1, 0><<<dim3(64, 3), blk, 0, stream>>>(Xn, Wo, bo, (float*)d_out, 8192, 384, 384, 1.0f);
}